// Round 14
// baseline (295.088 us; speedup 1.0000x reference)
//
#include <hip/hip_runtime.h>
#include <cstdint>
#include <cstddef>

#define BATCH 2
#define SEQ 2048
#define DMODEL 1024
#define NHEAD 16
#define DFF 4096
#define MTOT (BATCH * SEQ) /* 4096 */

typedef __bf16 bf16x8 __attribute__((ext_vector_type(8)));
typedef __bf16 bf16x4 __attribute__((ext_vector_type(4)));
typedef short s16x4 __attribute__((ext_vector_type(4)));
typedef float f32x4 __attribute__((ext_vector_type(4)));

// async global->LDS, 16B/lane; LDS dest = wave-uniform base + lane*16 (m104).
__device__ __forceinline__ void gload_lds16(const void* g, void* l) {
  __builtin_amdgcn_global_load_lds(
      (__attribute__((address_space(1))) void*)(uintptr_t)g,
      (__attribute__((address_space(3))) void*)(uint32_t)(uintptr_t)l,
      16, 0, 0);
}

// ---------------------------------------------------------------------------
// fp32 [K,N] -> bf16 [N,K] transpose (weights -> B^T layout)
// ---------------------------------------------------------------------------
__global__ __launch_bounds__(256) void k_transpose_to_bf16(
    const float* __restrict__ w, __bf16* __restrict__ wt, int K, int N) {
  __shared__ float t[32][33];
  const int n0 = blockIdx.x * 32, k0 = blockIdx.y * 32;
  const int tx = threadIdx.x & 31, ty = threadIdx.x >> 5;
#pragma unroll
  for (int i = ty; i < 32; i += 8) t[i][tx] = w[(size_t)(k0 + i) * N + n0 + tx];
  __syncthreads();
#pragma unroll
  for (int i = ty; i < 32; i += 8)
    wt[(size_t)(n0 + i) * K + k0 + tx] = (__bf16)t[tx][i];
}

__global__ __launch_bounds__(256) void k_cvt_bf16(
    const float* __restrict__ in, __bf16* __restrict__ out, int n) {
  const int i = (blockIdx.x * 256 + threadIdx.x) * 4;
  if (i >= n) return;
  const float4 v = *(const float4*)(in + i);
  bf16x4 r;
  r[0] = (__bf16)v.x; r[1] = (__bf16)v.y; r[2] = (__bf16)v.z; r[3] = (__bf16)v.w;
  *(bf16x4*)(out + i) = r;
}

__global__ void k_concat3(const float* __restrict__ a, const float* __restrict__ b,
                          const float* __restrict__ c, float* __restrict__ o) {
  const int i = blockIdx.x * 256 + threadIdx.x;
  if (i >= 3072) return;
  o[i] = (i < 1024) ? a[i] : (i < 2048) ? b[i - 1024] : c[i - 2048];
}

// bf16 V-section transpose: qkvb[b*S+s][2048+c] -> vT[b*1024+c][s]
__global__ __launch_bounds__(256) void k_transpose_v(
    const __bf16* __restrict__ qkvb, __bf16* __restrict__ vT) {
  __shared__ __bf16 t[32][33];
  const int s0 = blockIdx.x * 32, c0 = blockIdx.y * 32, b = blockIdx.z;
  const int tx = threadIdx.x & 31, ty = threadIdx.x >> 5;
#pragma unroll
  for (int i = ty; i < 32; i += 8)
    t[i][tx] = qkvb[(size_t)(b * SEQ + s0 + i) * 3072 + 2048 + c0 + tx];
  __syncthreads();
#pragma unroll
  for (int i = ty; i < 32; i += 8)
    vT[((size_t)b * 1024 + c0 + i) * SEQ + s0 + tx] = t[tx][i];
}

// ---------------------------------------------------------------------------
// bf16 MFMA GEMM (R9-verified: round-2 body + XCD swizzle, plain epilogue).
// BM=MF*32, BN=128, BK=64, 4 waves (2x2). nwg % 8 == 0 on all grids.
// ---------------------------------------------------------------------------
template <int MF, bool RELU, typename OutT>
__global__ __launch_bounds__(256) void k_gemm(
    const __bf16* __restrict__ A, const __bf16* __restrict__ BT,
    const float* __restrict__ bias, OutT* __restrict__ C, int M, int N, int K) {
  __shared__ __bf16 sA[MF * 32 * 64];
  __shared__ __bf16 sB[128 * 64];
  const int tid = threadIdx.x, lane = tid & 63, wv = tid >> 6;
  const int wm = wv >> 1, wn = wv & 1;
  const int lrow = lane & 15, hi = lane >> 4;
  const int nwg = gridDim.x * gridDim.y;
  const int flat = blockIdx.y * gridDim.x + blockIdx.x;
  const int cpx = nwg >> 3;
  const int swzb = (flat & 7) * cpx + (flat >> 3);
  const int m0 = (swzb / gridDim.x) * (MF * 32);
  const int n0 = (swzb % gridDim.x) * 128;
  const int srow = lane >> 3;
  const int scolE = ((lane & 7) ^ srow) * 8;
  const int swz = (lrow & 7) << 4;

  f32x4 acc[MF][4];
#pragma unroll
  for (int r = 0; r < MF; ++r)
#pragma unroll
    for (int c = 0; c < 4; ++c) acc[r][c] = f32x4{0.f, 0.f, 0.f, 0.f};

  for (int k0 = 0; k0 < K; k0 += 64) {
    __syncthreads();
#pragma unroll
    for (int rb = wv; rb < MF * 4; rb += 4) {
      const int row = rb * 8 + srow;
      gload_lds16(A + (size_t)(m0 + row) * K + k0 + scolE, &sA[rb * 512]);
    }
#pragma unroll
    for (int rb = wv; rb < 16; rb += 4) {
      const int row = rb * 8 + srow;
      gload_lds16(BT + (size_t)(n0 + row) * K + k0 + scolE, &sB[rb * 512]);
    }
    __syncthreads();
#pragma unroll
    for (int kc = 0; kc < 2; ++kc) {
      bf16x8 af[MF], bfr[4];
#pragma unroll
      for (int r = 0; r < MF; ++r) {
        const int row = wm * (MF * 16) + r * 16 + lrow;
        af[r] = *(const bf16x8*)((const char*)sA + row * 128 + ((kc * 64 + hi * 16) ^ swz));
      }
#pragma unroll
      for (int c = 0; c < 4; ++c) {
        const int row = wn * 64 + c * 16 + lrow;
        bfr[c] = *(const bf16x8*)((const char*)sB + row * 128 + ((kc * 64 + hi * 16) ^ swz));
      }
#pragma unroll
      for (int r = 0; r < MF; ++r)
#pragma unroll
        for (int c = 0; c < 4; ++c)
          acc[r][c] = __builtin_amdgcn_mfma_f32_16x16x32_bf16(af[r], bfr[c],
                                                              acc[r][c], 0, 0, 0);
    }
  }

#pragma unroll
  for (int r = 0; r < MF; ++r) {
    const int row = m0 + wm * (MF * 16) + r * 16 + hi * 4;
#pragma unroll
    for (int c = 0; c < 4; ++c) {
      const int col = n0 + wn * 64 + c * 16 + lrow;
      const float bb = bias[col];
#pragma unroll
      for (int j = 0; j < 4; ++j) {
        float v = acc[r][c][j] + bb;
        if (RELU) v = fmaxf(v, 0.f);
        C[(size_t)(row + j) * N + col] = (OutT)v;
      }
    }
  }
}

// ---------------------------------------------------------------------------
// Flash attention — R13 hazard-safe body (all MFMAs are builtins), widened
// to KVBLK=128 (R11's staging map). Sync protocol unchanged: sync; issue
// gload_lds; sync; compute — zero cross-barrier traffic. The R11 NaN is
// attributed to the asm PV MFMA's missing hazard modeling (R13 theory);
// this round is that theory's clean test.
// ---------------------------------------------------------------------------
__global__ __launch_bounds__(256) void k_attn(
    const __bf16* __restrict__ qkv, const __bf16* __restrict__ vT,
    const float* __restrict__ mask, __bf16* __restrict__ out) {
  const int qb = blockIdx.x, h = blockIdx.y, b = blockIdx.z;
  const int tid = threadIdx.x, lane = tid & 63, wv = tid >> 6;
  const int lrow = lane & 15, hi = lane >> 4;

  __shared__ __bf16 sK[128 * 64];  // [key][d], 128B swizzled rows
  __shared__ __bf16 sV0[64 * 64];  // [d][key 0..64), swizzled
  __shared__ __bf16 sV1[64 * 64];  // [d][key 64..128), swizzled

  const size_t base = (size_t)b * SEQ * 3072;
  const __bf16* Qb = qkv + base + h * 64;
  const __bf16* Kb = qkv + base + 1024 + h * 64;
  const __bf16* vTb = vT + ((size_t)b * 1024 + h * 64) * SEQ;
  const float* maskb = mask + (size_t)b * SEQ;

  const int q0 = qb * 64 + wv * 16;
  const bf16x8 qf0 = *(const bf16x8*)&Qb[(size_t)(q0 + lrow) * 3072 + hi * 8];
  const bf16x8 qf1 = *(const bf16x8*)&Qb[(size_t)(q0 + lrow) * 3072 + 32 + hi * 8];

  float m_r = -3e38f, l_r = 0.f;
  f32x4 o[4];
#pragma unroll
  for (int d = 0; d < 4; ++d) o[d] = f32x4{0.f, 0.f, 0.f, 0.f};

  const int srow = lane >> 3;
  const int scolE = ((lane & 7) ^ srow) * 8;
  const int swz = (lrow & 7) << 4;

  for (int k0 = 0; k0 < SEQ; k0 += 128) {
    __syncthreads();
    // K: 128 rows x 64 d (16 chunks of 8 rows)
#pragma unroll
    for (int rb = wv; rb < 16; rb += 4) {
      const int row = rb * 8 + srow;
      gload_lds16(Kb + (size_t)(k0 + row) * 3072 + scolE, &sK[rb * 512]);
    }
    // V halves: 64 d-rows x 64 keys each
#pragma unroll
    for (int rb = wv; rb < 8; rb += 4) {
      const int row = rb * 8 + srow;
      gload_lds16(vTb + (size_t)row * SEQ + k0 + scolE, &sV0[rb * 512]);
      gload_lds16(vTb + (size_t)row * SEQ + k0 + 64 + scolE, &sV1[rb * 512]);
    }
    __syncthreads();

    // S^T = K * Q^T : st[t4][j] = S[key = t4*16 + 4hi + j][q = lrow]
    f32x4 st[8];
#pragma unroll
    for (int t4 = 0; t4 < 8; ++t4) {
      const char* rp = (const char*)sK + (t4 * 16 + lrow) * 128;
      const bf16x8 ka = *(const bf16x8*)(rp + ((hi * 16) ^ swz));
      const bf16x8 kb = *(const bf16x8*)(rp + ((64 + hi * 16) ^ swz));
      f32x4 a = f32x4{0.f, 0.f, 0.f, 0.f};
      a = __builtin_amdgcn_mfma_f32_16x16x32_bf16(ka, qf0, a, 0, 0, 0);
      a = __builtin_amdgcn_mfma_f32_16x16x32_bf16(kb, qf1, a, 0, 0, 0);
      st[t4] = a;
    }

    float pm = -3e38f;
#pragma unroll
    for (int t4 = 0; t4 < 8; ++t4) {
      const f32x4 mk = *(const f32x4*)&maskb[k0 + t4 * 16 + hi * 4];
#pragma unroll
      for (int j = 0; j < 4; ++j) {
        st[t4][j] = st[t4][j] * 0.125f + mk[j];
        pm = fmaxf(pm, st[t4][j]);
      }
    }
    pm = fmaxf(pm, __shfl_xor(pm, 16));
    pm = fmaxf(pm, __shfl_xor(pm, 32));

    const float mn = fmaxf(m_r, pm);
    const float so = __expf(m_r - mn);
    m_r = mn;
    float rs = 0.f;
#pragma unroll
    for (int t4 = 0; t4 < 8; ++t4)
#pragma unroll
      for (int j = 0; j < 4; ++j) {
        st[t4][j] = __expf(st[t4][j] - mn);
        rs += st[t4][j];
      }
    rs += __shfl_xor(rs, 16);
    rs += __shfl_xor(rs, 32);
    l_r = l_r * so + rs;

    float so_o[4];
#pragma unroll
    for (int jj = 0; jj < 4; ++jj) so_o[jj] = __shfl(so, hi * 4 + jj);
#pragma unroll
    for (int d = 0; d < 4; ++d)
#pragma unroll
      for (int jj = 0; jj < 4; ++jj) o[d][jj] *= so_o[jj];

    // P -> bf16 A-frags of 16x16x16 (k = 4hi+j), as <4 x i16> for the builtin
    s16x4 pa[8];
#pragma unroll
    for (int t4 = 0; t4 < 8; ++t4)
#pragma unroll
      for (int j = 0; j < 4; ++j) {
        const __bf16 pb = (__bf16)st[t4][j];
        pa[t4][j] = __builtin_bit_cast(short, pb);
      }

#pragma unroll
    for (int d = 0; d < 4; ++d) {
      const char* rp0 = (const char*)sV0 + (d * 16 + lrow) * 128;
      const char* rp1 = (const char*)sV1 + (d * 16 + lrow) * 128;
#pragma unroll
      for (int t4 = 0; t4 < 4; ++t4) {
        const s16x4 vb0 = *(const s16x4*)(rp0 + ((t4 * 32 + hi * 8) ^ swz));
        o[d] = __builtin_amdgcn_mfma_f32_16x16x16bf16_1k(pa[t4], vb0, o[d], 0, 0, 0);
        const s16x4 vb1 = *(const s16x4*)(rp1 + ((t4 * 32 + hi * 8) ^ swz));
        o[d] = __builtin_amdgcn_mfma_f32_16x16x16bf16_1k(pa[4 + t4], vb1, o[d], 0, 0, 0);
      }
    }
  }

  __syncthreads();
  float linv[4];
#pragma unroll
  for (int jj = 0; jj < 4; ++jj) linv[jj] = 1.0f / __shfl(l_r, hi * 4 + jj);
#pragma unroll
  for (int d = 0; d < 4; ++d)
#pragma unroll
    for (int jj = 0; jj < 4; ++jj)
      out[((size_t)b * SEQ + q0 + hi * 4 + jj) * DMODEL + h * 64 + d * 16 + lrow] =
          (__bf16)(o[d][jj] * linv[jj]);
}

// ---------------------------------------------------------------------------
// out = LayerNorm(x + y) * g + beta ; writes fp32 residual and optional bf16
// ---------------------------------------------------------------------------
__global__ __launch_bounds__(256) void k_add_ln(
    const float* __restrict__ x, const float* __restrict__ y,
    const float* __restrict__ g, const float* __restrict__ be,
    float* __restrict__ of, __bf16* __restrict__ ob) {
  const int row = blockIdx.x, tid = threadIdx.x;
  const float4 a = ((const float4*)(x + (size_t)row * 1024))[tid];
  const float4 b = ((const float4*)(y + (size_t)row * 1024))[tid];
  const float v0 = a.x + b.x, v1 = a.y + b.y, v2 = a.z + b.z, v3 = a.w + b.w;
  float s = v0 + v1 + v2 + v3;
  float s2 = v0 * v0 + v1 * v1 + v2 * v2 + v3 * v3;
#pragma unroll
  for (int off = 32; off > 0; off >>= 1) {
    s += __shfl_xor(s, off);
    s2 += __shfl_xor(s2, off);
  }
  __shared__ float red[2][4];
  const int wv = tid >> 6, lane = tid & 63;
  if (lane == 0) { red[0][wv] = s; red[1][wv] = s2; }
  __syncthreads();
  s = red[0][0] + red[0][1] + red[0][2] + red[0][3];
  s2 = red[1][0] + red[1][1] + red[1][2] + red[1][3];
  const float mean = s * (1.0f / 1024.0f);
  const float var = s2 * (1.0f / 1024.0f) - mean * mean;
  const float rstd = rsqrtf(var + 1e-5f);
  const float4 gg = ((const float4*)g)[tid];
  const float4 bt = ((const float4*)be)[tid];
  float4 r;
  r.x = (v0 - mean) * rstd * gg.x + bt.x;
  r.y = (v1 - mean) * rstd * gg.y + bt.y;
  r.z = (v2 - mean) * rstd * gg.z + bt.z;
  r.w = (v3 - mean) * rstd * gg.w + bt.w;
  ((float4*)(of + (size_t)row * 1024))[tid] = r;
  if (ob) {
    bf16x4 rb;
    rb[0] = (__bf16)r.x; rb[1] = (__bf16)r.y; rb[2] = (__bf16)r.z; rb[3] = (__bf16)r.w;
    *(bf16x4*)(ob + (size_t)row * 1024 + tid * 4) = rb;
  }
}

// ---------------------------------------------------------------------------
extern "C" void kernel_launch(void* const* d_in, const int* in_sizes, int n_in,
                              void* d_out, int out_size, void* d_ws, size_t ws_size,
                              hipStream_t stream) {
  const float* x = (const float*)d_in[0];
  const float* src_mask = (const float*)d_in[1];
  const float* w_q = (const float*)d_in[2];
  const float* b_q = (const float*)d_in[3];
  const float* w_k = (const float*)d_in[4];
  const float* b_k = (const float*)d_in[5];
  const float* w_v = (const float*)d_in[6];
  const float* b_v = (const float*)d_in[7];
  const float* w_o = (const float*)d_in[8];
  const float* b_o = (const float*)d_in[9];
  const float* w_ff1 = (const float*)d_in[10];
  const float* b_ff1 = (const float*)d_in[11];
  const float* w_ff2 = (const float*)d_in[12];
  const float* b_ff2 = (const float*)d_in[13];
  const float* ln1_g = (const float*)d_in[14];
  const float* ln1_b = (const float*)d_in[15];
  const float* ln2_g = (const float*)d_in[16];
  const float* ln2_b = (const float*)d_in[17];

  char* ws = (char*)d_ws;
  constexpr size_t O_WQKVT = 0;                               // 3072x1024 bf16
  constexpr size_t O_WOT = O_WQKVT + 3072ull * 1024 * 2;      // 1024x1024 bf16
  constexpr size_t O_WFF1T = O_WOT + 1024ull * 1024 * 2;      // 4096x1024 bf16
  constexpr size_t O_WFF2T = O_WFF1T + 4096ull * 1024 * 2;    // 1024x4096 bf16
  constexpr size_t O_BQKV = O_WFF2T + 4096ull * 1024 * 2;     // 3072 f32
  constexpr size_t O_XBF = O_BQKV + 3072ull * 4;              // 4096x1024 bf16
  constexpr size_t O_QKV = O_XBF + 4096ull * 1024 * 2;        // 4096x3072 bf16
  constexpr size_t O_ATTN = O_QKV + 4096ull * 3072 * 2;       // 4096x1024 bf16
  constexpr size_t O_PROJ = O_ATTN + 4096ull * 1024 * 2;      // 4096x1024 f32
  constexpr size_t O_H1F = O_PROJ + 4096ull * 1024 * 4;       // 4096x1024 f32
  constexpr size_t O_H1B = O_H1F + 4096ull * 1024 * 4;        // 4096x1024 bf16
  constexpr size_t O_VT = O_PROJ;   // 2x1024x2048 bf16 (dead before proj)
  constexpr size_t O_FF = O_QKV;    // 4096x4096 bf16 (reuse)
  constexpr size_t O_FF2 = O_PROJ;  // 4096x1024 f32 (reuse, after ln1)

  __bf16* wqkvT = (__bf16*)(ws + O_WQKVT);
  __bf16* woT = (__bf16*)(ws + O_WOT);
  __bf16* wff1T = (__bf16*)(ws + O_WFF1T);
  __bf16* wff2T = (__bf16*)(ws + O_WFF2T);
  float* bqkv = (float*)(ws + O_BQKV);
  __bf16* xbf = (__bf16*)(ws + O_XBF);
  __bf16* qkvb = (__bf16*)(ws + O_QKV);
  __bf16* attnb = (__bf16*)(ws + O_ATTN);
  float* proj = (float*)(ws + O_PROJ);
  float* h1f = (float*)(ws + O_H1F);
  __bf16* h1b = (__bf16*)(ws + O_H1B);
  __bf16* vT = (__bf16*)(ws + O_VT);
  __bf16* ffb = (__bf16*)(ws + O_FF);
  float* ff2 = (float*)(ws + O_FF2);

  // weight prep
  k_transpose_to_bf16<<<dim3(32, 32), 256, 0, stream>>>(w_q, wqkvT, 1024, 1024);
  k_transpose_to_bf16<<<dim3(32, 32), 256, 0, stream>>>(w_k, wqkvT + 1024 * 1024, 1024, 1024);
  k_transpose_to_bf16<<<dim3(32, 32), 256, 0, stream>>>(w_v, wqkvT + 2 * 1024 * 1024, 1024, 1024);
  k_transpose_to_bf16<<<dim3(32, 32), 256, 0, stream>>>(w_o, woT, 1024, 1024);
  k_transpose_to_bf16<<<dim3(128, 32), 256, 0, stream>>>(w_ff1, wff1T, 1024, 4096);
  k_transpose_to_bf16<<<dim3(32, 128), 256, 0, stream>>>(w_ff2, wff2T, 4096, 1024);
  k_concat3<<<12, 256, 0, stream>>>(b_q, b_k, b_v, bqkv);
  k_cvt_bf16<<<4096, 256, 0, stream>>>(x, xbf, MTOT * DMODEL);

  // fused QKV projection
  k_gemm<4, false, __bf16><<<dim3(24, 32), 256, 0, stream>>>(xbf, wqkvT, bqkv, qkvb,
                                                             MTOT, 3072, 1024);
  // V transpose for attention B-frags
  k_transpose_v<<<dim3(64, 32, 2), 256, 0, stream>>>(qkvb, vT);
  // attention (KVBLK=128, builtin MFMAs throughout)
  k_attn<<<dim3(SEQ / 64, NHEAD, BATCH), 256, 0, stream>>>(qkvb, vT, src_mask, attnb);
  // output projection (f32)
  k_gemm<2, false, float><<<dim3(8, 64), 256, 0, stream>>>(attnb, woT, b_o, proj,
                                                           MTOT, 1024, 1024);
  // ln1
  k_add_ln<<<4096, 256, 0, stream>>>(x, proj, ln1_g, ln1_b, h1f, h1b);
  // ff1 + relu
  k_gemm<4, true, __bf16><<<dim3(32, 32), 256, 0, stream>>>(h1b, wff1T, b_ff1, ffb,
                                                            MTOT, DFF, 1024);
  // ff2
  k_gemm<2, false, float><<<dim3(8, 64), 256, 0, stream>>>(ffb, wff2T, b_ff2, ff2,
                                                           MTOT, 1024, DFF);
  // ln2 -> d_out
  k_add_ln<<<4096, 256, 0, stream>>>(h1f, ff2, ln2_g, ln2_b, (float*)d_out, nullptr);
}

// Round 15
// 288.745 us; speedup vs baseline: 1.0220x; 1.0220x over previous
//
#include <hip/hip_runtime.h>
#include <cstdint>
#include <cstddef>

#define BATCH 2
#define SEQ 2048
#define DMODEL 1024
#define NHEAD 16
#define DFF 4096
#define MTOT (BATCH * SEQ) /* 4096 */

typedef __bf16 bf16x8 __attribute__((ext_vector_type(8)));
typedef __bf16 bf16x4 __attribute__((ext_vector_type(4)));
typedef short s16x4 __attribute__((ext_vector_type(4)));
typedef float f32x4 __attribute__((ext_vector_type(4)));

// async global->LDS, 16B/lane; LDS dest = wave-uniform base + lane*16 (m104).
__device__ __forceinline__ void gload_lds16(const void* g, void* l) {
  __builtin_amdgcn_global_load_lds(
      (__attribute__((address_space(1))) void*)(uintptr_t)g,
      (__attribute__((address_space(3))) void*)(uint32_t)(uintptr_t)l,
      16, 0, 0);
}

// ---------------------------------------------------------------------------
// fp32 [K,N] -> bf16 [N,K] transpose (weights -> B^T layout)
// ---------------------------------------------------------------------------
__global__ __launch_bounds__(256) void k_transpose_to_bf16(
    const float* __restrict__ w, __bf16* __restrict__ wt, int K, int N) {
  __shared__ float t[32][33];
  const int n0 = blockIdx.x * 32, k0 = blockIdx.y * 32;
  const int tx = threadIdx.x & 31, ty = threadIdx.x >> 5;
#pragma unroll
  for (int i = ty; i < 32; i += 8) t[i][tx] = w[(size_t)(k0 + i) * N + n0 + tx];
  __syncthreads();
#pragma unroll
  for (int i = ty; i < 32; i += 8)
    wt[(size_t)(n0 + i) * K + k0 + tx] = (__bf16)t[tx][i];
}

__global__ __launch_bounds__(256) void k_cvt_bf16(
    const float* __restrict__ in, __bf16* __restrict__ out, int n) {
  const int i = (blockIdx.x * 256 + threadIdx.x) * 4;
  if (i >= n) return;
  const float4 v = *(const float4*)(in + i);
  bf16x4 r;
  r[0] = (__bf16)v.x; r[1] = (__bf16)v.y; r[2] = (__bf16)v.z; r[3] = (__bf16)v.w;
  *(bf16x4*)(out + i) = r;
}

__global__ void k_concat3(const float* __restrict__ a, const float* __restrict__ b,
                          const float* __restrict__ c, float* __restrict__ o) {
  const int i = blockIdx.x * 256 + threadIdx.x;
  if (i >= 3072) return;
  o[i] = (i < 1024) ? a[i] : (i < 2048) ? b[i - 1024] : c[i - 2048];
}

// bf16 V-section transpose: qkvb[b*S+s][2048+c] -> vT[b*1024+c][s]
__global__ __launch_bounds__(256) void k_transpose_v(
    const __bf16* __restrict__ qkvb, __bf16* __restrict__ vT) {
  __shared__ __bf16 t[32][33];
  const int s0 = blockIdx.x * 32, c0 = blockIdx.y * 32, b = blockIdx.z;
  const int tx = threadIdx.x & 31, ty = threadIdx.x >> 5;
#pragma unroll
  for (int i = ty; i < 32; i += 8)
    t[i][tx] = qkvb[(size_t)(b * SEQ + s0 + i) * 3072 + 2048 + c0 + tx];
  __syncthreads();
#pragma unroll
  for (int i = ty; i < 32; i += 8)
    vT[((size_t)b * 1024 + c0 + i) * SEQ + s0 + tx] = t[tx][i];
}

// ---------------------------------------------------------------------------
// bf16 MFMA GEMM (R9-verified: round-2 body + XCD swizzle, plain epilogue).
// BM=MF*32, BN=128, BK=64, 4 waves (2x2). nwg % 8 == 0 on all grids.
// ---------------------------------------------------------------------------
template <int MF, bool RELU, typename OutT>
__global__ __launch_bounds__(256) void k_gemm(
    const __bf16* __restrict__ A, const __bf16* __restrict__ BT,
    const float* __restrict__ bias, OutT* __restrict__ C, int M, int N, int K) {
  __shared__ __bf16 sA[MF * 32 * 64];
  __shared__ __bf16 sB[128 * 64];
  const int tid = threadIdx.x, lane = tid & 63, wv = tid >> 6;
  const int wm = wv >> 1, wn = wv & 1;
  const int lrow = lane & 15, hi = lane >> 4;
  const int nwg = gridDim.x * gridDim.y;
  const int flat = blockIdx.y * gridDim.x + blockIdx.x;
  const int cpx = nwg >> 3;
  const int swzb = (flat & 7) * cpx + (flat >> 3);
  const int m0 = (swzb / gridDim.x) * (MF * 32);
  const int n0 = (swzb % gridDim.x) * 128;
  const int srow = lane >> 3;
  const int scolE = ((lane & 7) ^ srow) * 8;
  const int swz = (lrow & 7) << 4;

  f32x4 acc[MF][4];
#pragma unroll
  for (int r = 0; r < MF; ++r)
#pragma unroll
    for (int c = 0; c < 4; ++c) acc[r][c] = f32x4{0.f, 0.f, 0.f, 0.f};

  for (int k0 = 0; k0 < K; k0 += 64) {
    __syncthreads();
#pragma unroll
    for (int rb = wv; rb < MF * 4; rb += 4) {
      const int row = rb * 8 + srow;
      gload_lds16(A + (size_t)(m0 + row) * K + k0 + scolE, &sA[rb * 512]);
    }
#pragma unroll
    for (int rb = wv; rb < 16; rb += 4) {
      const int row = rb * 8 + srow;
      gload_lds16(BT + (size_t)(n0 + row) * K + k0 + scolE, &sB[rb * 512]);
    }
    __syncthreads();
#pragma unroll
    for (int kc = 0; kc < 2; ++kc) {
      bf16x8 af[MF], bfr[4];
#pragma unroll
      for (int r = 0; r < MF; ++r) {
        const int row = wm * (MF * 16) + r * 16 + lrow;
        af[r] = *(const bf16x8*)((const char*)sA + row * 128 + ((kc * 64 + hi * 16) ^ swz));
      }
#pragma unroll
      for (int c = 0; c < 4; ++c) {
        const int row = wn * 64 + c * 16 + lrow;
        bfr[c] = *(const bf16x8*)((const char*)sB + row * 128 + ((kc * 64 + hi * 16) ^ swz));
      }
#pragma unroll
      for (int r = 0; r < MF; ++r)
#pragma unroll
        for (int c = 0; c < 4; ++c)
          acc[r][c] = __builtin_amdgcn_mfma_f32_16x16x32_bf16(af[r], bfr[c],
                                                              acc[r][c], 0, 0, 0);
    }
  }

#pragma unroll
  for (int r = 0; r < MF; ++r) {
    const int row = m0 + wm * (MF * 16) + r * 16 + hi * 4;
#pragma unroll
    for (int c = 0; c < 4; ++c) {
      const int col = n0 + wn * 64 + c * 16 + lrow;
      const float bb = bias[col];
#pragma unroll
      for (int j = 0; j < 4; ++j) {
        float v = acc[r][c][j] + bb;
        if (RELU) v = fmaxf(v, 0.f);
        C[(size_t)(row + j) * N + col] = (OutT)v;
      }
    }
  }
}

// ---------------------------------------------------------------------------
// Flash attention — R13 hazard-safe body (all MFMAs builtins), KVBLK=64,
// DOUBLE-BUFFERED issue-early staging: stage(t+1) is issued right after the
// loop-top __syncthreads and stays in flight through compute(t); the next
// iteration's __syncthreads (vmcnt0+lgkmcnt0 drain + barrier) completes it.
// R6's identical structure NaN'd with the ASM PV MFMA; R13/R14 established
// the asm hazard-modeling gap as the cause. This is the clean dbuf retest.
// ---------------------------------------------------------------------------
__global__ __launch_bounds__(256) void k_attn(
    const __bf16* __restrict__ qkv, const __bf16* __restrict__ vT,
    const float* __restrict__ mask, __bf16* __restrict__ out) {
  const int qb = blockIdx.x, h = blockIdx.y, b = blockIdx.z;
  const int tid = threadIdx.x, lane = tid & 63, wv = tid >> 6;
  const int lrow = lane & 15, hi = lane >> 4;

  __shared__ __bf16 sK[2][64 * 64];  // [buf][key][d], swizzled
  __shared__ __bf16 sV[2][64 * 64];  // [buf][d][key], swizzled

  const size_t base = (size_t)b * SEQ * 3072;
  const __bf16* Qb = qkv + base + h * 64;
  const __bf16* Kb = qkv + base + 1024 + h * 64;
  const __bf16* vTb = vT + ((size_t)b * 1024 + h * 64) * SEQ;
  const float* maskb = mask + (size_t)b * SEQ;

  const int q0 = qb * 64 + wv * 16;
  const bf16x8 qf0 = *(const bf16x8*)&Qb[(size_t)(q0 + lrow) * 3072 + hi * 8];
  const bf16x8 qf1 = *(const bf16x8*)&Qb[(size_t)(q0 + lrow) * 3072 + 32 + hi * 8];

  float m_r = -3e38f, l_r = 0.f;
  f32x4 o[4];
#pragma unroll
  for (int d = 0; d < 4; ++d) o[d] = f32x4{0.f, 0.f, 0.f, 0.f};

  const int srow = lane >> 3;
  const int scolE = ((lane & 7) ^ srow) * 8;
  const int swz = (lrow & 7) << 4;

  auto stage = [&](int t) {
    const int k0s = t * 64;
    __bf16* dK = sK[t & 1];
    __bf16* dV = sV[t & 1];
#pragma unroll
    for (int r = 0; r < 2; ++r) {
      const int rb = r * 4 + wv;
      const int row = rb * 8 + srow;
      gload_lds16(Kb + (size_t)(k0s + row) * 3072 + scolE, &dK[rb * 512]);
      gload_lds16(vTb + (size_t)row * SEQ + k0s + scolE, &dV[rb * 512]);
    }
  };

  stage(0);
  const int NT = SEQ / 64;
  for (int t = 0; t < NT; ++t) {
    __syncthreads();  // drains vmcnt+lgkmcnt: stage(t) landed block-wide
    if (t + 1 < NT) stage(t + 1);  // in flight through compute(t)
    const __bf16* cK = sK[t & 1];
    const __bf16* cV = sV[t & 1];
    const int k0 = t * 64;

    // S^T = K * Q^T : st[t4][j] = S[key = t4*16 + 4hi + j][q = lrow]
    f32x4 st[4];
#pragma unroll
    for (int t4 = 0; t4 < 4; ++t4) {
      const char* rp = (const char*)cK + (t4 * 16 + lrow) * 128;
      const bf16x8 ka = *(const bf16x8*)(rp + ((hi * 16) ^ swz));
      const bf16x8 kb = *(const bf16x8*)(rp + ((64 + hi * 16) ^ swz));
      f32x4 a = f32x4{0.f, 0.f, 0.f, 0.f};
      a = __builtin_amdgcn_mfma_f32_16x16x32_bf16(ka, qf0, a, 0, 0, 0);
      a = __builtin_amdgcn_mfma_f32_16x16x32_bf16(kb, qf1, a, 0, 0, 0);
      st[t4] = a;
    }

    float pm = -3e38f;
#pragma unroll
    for (int t4 = 0; t4 < 4; ++t4) {
      const f32x4 mk = *(const f32x4*)&maskb[k0 + t4 * 16 + hi * 4];
#pragma unroll
      for (int j = 0; j < 4; ++j) {
        st[t4][j] = st[t4][j] * 0.125f + mk[j];
        pm = fmaxf(pm, st[t4][j]);
      }
    }
    pm = fmaxf(pm, __shfl_xor(pm, 16));
    pm = fmaxf(pm, __shfl_xor(pm, 32));

    const float mn = fmaxf(m_r, pm);
    const float so = __expf(m_r - mn);
    m_r = mn;
    float rs = 0.f;
#pragma unroll
    for (int t4 = 0; t4 < 4; ++t4)
#pragma unroll
      for (int j = 0; j < 4; ++j) {
        st[t4][j] = __expf(st[t4][j] - mn);
        rs += st[t4][j];
      }
    rs += __shfl_xor(rs, 16);
    rs += __shfl_xor(rs, 32);
    l_r = l_r * so + rs;

    float so_o[4];
#pragma unroll
    for (int jj = 0; jj < 4; ++jj) so_o[jj] = __shfl(so, hi * 4 + jj);
#pragma unroll
    for (int d = 0; d < 4; ++d)
#pragma unroll
      for (int jj = 0; jj < 4; ++jj) o[d][jj] *= so_o[jj];

    // P -> bf16 A-frags of 16x16x16 (k = 4hi+j), as <4 x i16> for the builtin
    s16x4 pa[4];
#pragma unroll
    for (int t4 = 0; t4 < 4; ++t4)
#pragma unroll
      for (int j = 0; j < 4; ++j) {
        const __bf16 pb = (__bf16)st[t4][j];
        pa[t4][j] = __builtin_bit_cast(short, pb);
      }

#pragma unroll
    for (int d = 0; d < 4; ++d) {
      const char* rp = (const char*)cV + (d * 16 + lrow) * 128;
#pragma unroll
      for (int t4 = 0; t4 < 4; ++t4) {
        const s16x4 vb = *(const s16x4*)(rp + ((t4 * 32 + hi * 8) ^ swz));
        o[d] = __builtin_amdgcn_mfma_f32_16x16x16bf16_1k(pa[t4], vb, o[d], 0, 0, 0);
      }
    }
  }

  __syncthreads();
  float linv[4];
#pragma unroll
  for (int jj = 0; jj < 4; ++jj) linv[jj] = 1.0f / __shfl(l_r, hi * 4 + jj);
#pragma unroll
  for (int d = 0; d < 4; ++d)
#pragma unroll
    for (int jj = 0; jj < 4; ++jj)
      out[((size_t)b * SEQ + q0 + hi * 4 + jj) * DMODEL + h * 64 + d * 16 + lrow] =
          (__bf16)(o[d][jj] * linv[jj]);
}

// ---------------------------------------------------------------------------
// out = LayerNorm(x + y) * g + beta ; writes fp32 residual and optional bf16
// ---------------------------------------------------------------------------
__global__ __launch_bounds__(256) void k_add_ln(
    const float* __restrict__ x, const float* __restrict__ y,
    const float* __restrict__ g, const float* __restrict__ be,
    float* __restrict__ of, __bf16* __restrict__ ob) {
  const int row = blockIdx.x, tid = threadIdx.x;
  const float4 a = ((const float4*)(x + (size_t)row * 1024))[tid];
  const float4 b = ((const float4*)(y + (size_t)row * 1024))[tid];
  const float v0 = a.x + b.x, v1 = a.y + b.y, v2 = a.z + b.z, v3 = a.w + b.w;
  float s = v0 + v1 + v2 + v3;
  float s2 = v0 * v0 + v1 * v1 + v2 * v2 + v3 * v3;
#pragma unroll
  for (int off = 32; off > 0; off >>= 1) {
    s += __shfl_xor(s, off);
    s2 += __shfl_xor(s2, off);
  }
  __shared__ float red[2][4];
  const int wv = tid >> 6, lane = tid & 63;
  if (lane == 0) { red[0][wv] = s; red[1][wv] = s2; }
  __syncthreads();
  s = red[0][0] + red[0][1] + red[0][2] + red[0][3];
  s2 = red[1][0] + red[1][1] + red[1][2] + red[1][3];
  const float mean = s * (1.0f / 1024.0f);
  const float var = s2 * (1.0f / 1024.0f) - mean * mean;
  const float rstd = rsqrtf(var + 1e-5f);
  const float4 gg = ((const float4*)g)[tid];
  const float4 bt = ((const float4*)be)[tid];
  float4 r;
  r.x = (v0 - mean) * rstd * gg.x + bt.x;
  r.y = (v1 - mean) * rstd * gg.y + bt.y;
  r.z = (v2 - mean) * rstd * gg.z + bt.z;
  r.w = (v3 - mean) * rstd * gg.w + bt.w;
  ((float4*)(of + (size_t)row * 1024))[tid] = r;
  if (ob) {
    bf16x4 rb;
    rb[0] = (__bf16)r.x; rb[1] = (__bf16)r.y; rb[2] = (__bf16)r.z; rb[3] = (__bf16)r.w;
    *(bf16x4*)(ob + (size_t)row * 1024 + tid * 4) = rb;
  }
}

// ---------------------------------------------------------------------------
extern "C" void kernel_launch(void* const* d_in, const int* in_sizes, int n_in,
                              void* d_out, int out_size, void* d_ws, size_t ws_size,
                              hipStream_t stream) {
  const float* x = (const float*)d_in[0];
  const float* src_mask = (const float*)d_in[1];
  const float* w_q = (const float*)d_in[2];
  const float* b_q = (const float*)d_in[3];
  const float* w_k = (const float*)d_in[4];
  const float* b_k = (const float*)d_in[5];
  const float* w_v = (const float*)d_in[6];
  const float* b_v = (const float*)d_in[7];
  const float* w_o = (const float*)d_in[8];
  const float* b_o = (const float*)d_in[9];
  const float* w_ff1 = (const float*)d_in[10];
  const float* b_ff1 = (const float*)d_in[11];
  const float* w_ff2 = (const float*)d_in[12];
  const float* b_ff2 = (const float*)d_in[13];
  const float* ln1_g = (const float*)d_in[14];
  const float* ln1_b = (const float*)d_in[15];
  const float* ln2_g = (const float*)d_in[16];
  const float* ln2_b = (const float*)d_in[17];

  char* ws = (char*)d_ws;
  constexpr size_t O_WQKVT = 0;                               // 3072x1024 bf16
  constexpr size_t O_WOT = O_WQKVT + 3072ull * 1024 * 2;      // 1024x1024 bf16
  constexpr size_t O_WFF1T = O_WOT + 1024ull * 1024 * 2;      // 4096x1024 bf16
  constexpr size_t O_WFF2T = O_WFF1T + 4096ull * 1024 * 2;    // 1024x4096 bf16
  constexpr size_t O_BQKV = O_WFF2T + 4096ull * 1024 * 2;     // 3072 f32
  constexpr size_t O_XBF = O_BQKV + 3072ull * 4;              // 4096x1024 bf16
  constexpr size_t O_QKV = O_XBF + 4096ull * 1024 * 2;        // 4096x3072 bf16
  constexpr size_t O_ATTN = O_QKV + 4096ull * 3072 * 2;       // 4096x1024 bf16
  constexpr size_t O_PROJ = O_ATTN + 4096ull * 1024 * 2;      // 4096x1024 f32
  constexpr size_t O_H1F = O_PROJ + 4096ull * 1024 * 4;       // 4096x1024 f32
  constexpr size_t O_H1B = O_H1F + 4096ull * 1024 * 4;        // 4096x1024 bf16
  constexpr size_t O_VT = O_PROJ;   // 2x1024x2048 bf16 (dead before proj)
  constexpr size_t O_FF = O_QKV;    // 4096x4096 bf16 (reuse)
  constexpr size_t O_FF2 = O_PROJ;  // 4096x1024 f32 (reuse, after ln1)

  __bf16* wqkvT = (__bf16*)(ws + O_WQKVT);
  __bf16* woT = (__bf16*)(ws + O_WOT);
  __bf16* wff1T = (__bf16*)(ws + O_WFF1T);
  __bf16* wff2T = (__bf16*)(ws + O_WFF2T);
  float* bqkv = (float*)(ws + O_BQKV);
  __bf16* xbf = (__bf16*)(ws + O_XBF);
  __bf16* qkvb = (__bf16*)(ws + O_QKV);
  __bf16* attnb = (__bf16*)(ws + O_ATTN);
  float* proj = (float*)(ws + O_PROJ);
  float* h1f = (float*)(ws + O_H1F);
  __bf16* h1b = (__bf16*)(ws + O_H1B);
  __bf16* vT = (__bf16*)(ws + O_VT);
  __bf16* ffb = (__bf16*)(ws + O_FF);
  float* ff2 = (float*)(ws + O_FF2);

  // weight prep
  k_transpose_to_bf16<<<dim3(32, 32), 256, 0, stream>>>(w_q, wqkvT, 1024, 1024);
  k_transpose_to_bf16<<<dim3(32, 32), 256, 0, stream>>>(w_k, wqkvT + 1024 * 1024, 1024, 1024);
  k_transpose_to_bf16<<<dim3(32, 32), 256, 0, stream>>>(w_v, wqkvT + 2 * 1024 * 1024, 1024, 1024);
  k_transpose_to_bf16<<<dim3(32, 32), 256, 0, stream>>>(w_o, woT, 1024, 1024);
  k_transpose_to_bf16<<<dim3(128, 32), 256, 0, stream>>>(w_ff1, wff1T, 1024, 4096);
  k_transpose_to_bf16<<<dim3(32, 128), 256, 0, stream>>>(w_ff2, wff2T, 4096, 1024);
  k_concat3<<<12, 256, 0, stream>>>(b_q, b_k, b_v, bqkv);
  k_cvt_bf16<<<4096, 256, 0, stream>>>(x, xbf, MTOT * DMODEL);

  // fused QKV projection
  k_gemm<4, false, __bf16><<<dim3(24, 32), 256, 0, stream>>>(xbf, wqkvT, bqkv, qkvb,
                                                             MTOT, 3072, 1024);
  // V transpose for attention B-frags
  k_transpose_v<<<dim3(64, 32, 2), 256, 0, stream>>>(qkvb, vT);
  // attention (KVBLK=64, builtin MFMAs, double-buffered issue-early staging)
  k_attn<<<dim3(SEQ / 64, NHEAD, BATCH), 256, 0, stream>>>(qkvb, vT, src_mask, attnb);
  // output projection (f32)
  k_gemm<2, false, float><<<dim3(8, 64), 256, 0, stream>>>(attnb, woT, b_o, proj,
                                                           MTOT, 1024, 1024);
  // ln1
  k_add_ln<<<4096, 256, 0, stream>>>(x, proj, ln1_g, ln1_b, h1f, h1b);
  // ff1 + relu
  k_gemm<4, true, __bf16><<<dim3(32, 32), 256, 0, stream>>>(h1b, wff1T, b_ff1, ffb,
                                                            MTOT, DFF, 1024);
  // ff2
  k_gemm<2, false, float><<<dim3(8, 64), 256, 0, stream>>>(ffb, wff2T, b_ff2, ff2,
                                                           MTOT, 1024, DFF);
  // ln2 -> d_out
  k_add_ln<<<4096, 256, 0, stream>>>(h1f, ff2, ln2_g, ln2_b, (float*)d_out, nullptr);
}

// Round 16
// 277.139 us; speedup vs baseline: 1.0648x; 1.0419x over previous
//
#include <hip/hip_runtime.h>
#include <cstdint>
#include <cstddef>

#define BATCH 2
#define SEQ 2048
#define DMODEL 1024
#define NHEAD 16
#define DFF 4096
#define MTOT (BATCH * SEQ) /* 4096 */

typedef __bf16 bf16x8 __attribute__((ext_vector_type(8)));
typedef __bf16 bf16x4 __attribute__((ext_vector_type(4)));
typedef short s16x4 __attribute__((ext_vector_type(4)));
typedef float f32x4 __attribute__((ext_vector_type(4)));

#define S_BARRIER() __builtin_amdgcn_s_barrier()
#define SCHED_FENCE() __builtin_amdgcn_sched_barrier(0)
#define VMCNT8() asm volatile("s_waitcnt vmcnt(8)" ::: "memory")
#define VMCNT4() asm volatile("s_waitcnt vmcnt(4)" ::: "memory")
#define VMCNT0() asm volatile("s_waitcnt vmcnt(0)" ::: "memory")

// async global->LDS, 16B/lane; LDS dest = wave-uniform base + lane*16 (m104).
__device__ __forceinline__ void gload_lds16(const void* g, void* l) {
  __builtin_amdgcn_global_load_lds(
      (__attribute__((address_space(1))) void*)(uintptr_t)g,
      (__attribute__((address_space(3))) void*)(uint32_t)(uintptr_t)l,
      16, 0, 0);
}

// ---------------------------------------------------------------------------
// fp32 [K,N] -> bf16 [N,K] transpose (weights -> B^T layout)
// ---------------------------------------------------------------------------
__global__ __launch_bounds__(256) void k_transpose_to_bf16(
    const float* __restrict__ w, __bf16* __restrict__ wt, int K, int N) {
  __shared__ float t[32][33];
  const int n0 = blockIdx.x * 32, k0 = blockIdx.y * 32;
  const int tx = threadIdx.x & 31, ty = threadIdx.x >> 5;
#pragma unroll
  for (int i = ty; i < 32; i += 8) t[i][tx] = w[(size_t)(k0 + i) * N + n0 + tx];
  __syncthreads();
#pragma unroll
  for (int i = ty; i < 32; i += 8)
    wt[(size_t)(n0 + i) * K + k0 + tx] = (__bf16)t[tx][i];
}

__global__ __launch_bounds__(256) void k_cvt_bf16(
    const float* __restrict__ in, __bf16* __restrict__ out, int n) {
  const int i = (blockIdx.x * 256 + threadIdx.x) * 4;
  if (i >= n) return;
  const float4 v = *(const float4*)(in + i);
  bf16x4 r;
  r[0] = (__bf16)v.x; r[1] = (__bf16)v.y; r[2] = (__bf16)v.z; r[3] = (__bf16)v.w;
  *(bf16x4*)(out + i) = r;
}

__global__ void k_concat3(const float* __restrict__ a, const float* __restrict__ b,
                          const float* __restrict__ c, float* __restrict__ o) {
  const int i = blockIdx.x * 256 + threadIdx.x;
  if (i >= 3072) return;
  o[i] = (i < 1024) ? a[i] : (i < 2048) ? b[i - 1024] : c[i - 2048];
}

// bf16 V-section transpose: qkvb[b*S+s][2048+c] -> vT[b*1024+c][s]
__global__ __launch_bounds__(256) void k_transpose_v(
    const __bf16* __restrict__ qkvb, __bf16* __restrict__ vT) {
  __shared__ __bf16 t[32][33];
  const int s0 = blockIdx.x * 32, c0 = blockIdx.y * 32, b = blockIdx.z;
  const int tx = threadIdx.x & 31, ty = threadIdx.x >> 5;
#pragma unroll
  for (int i = ty; i < 32; i += 8)
    t[i][tx] = qkvb[(size_t)(b * SEQ + s0 + i) * 3072 + 2048 + c0 + tx];
  __syncthreads();
#pragma unroll
  for (int i = ty; i < 32; i += 8)
    vT[((size_t)b * 1024 + c0 + i) * SEQ + s0 + tx] = t[tx][i];
}

// ---------------------------------------------------------------------------
// 256x256 deep-pipelined MFMA GEMM (T3+T4 counted-vmcnt, ALL-BUILTIN MFMAs).
// Independently retested now that the asm-MFMA attn (present in every prior
// failure) is fixed. 512 thr = 8 waves (2M x 4N); wave owns 128x64.
// LDS: period-4 slot ring of [256 rows][32 cols] per matrix = 128KB.
// Phase p: vmcnt(8) [stage(p) landed: 12 in flight -> drain oldest 4];
// s_barrier; sched_barrier(0); issue stage(p+3) [4 gloads/wave];
// 12 ds_read_b128; 32 MFMA (setprio-wrapped). Slot(p+3) last read at
// compute(p-1), whose reads retired before this barrier -> WAR-safe.
// Swizzle: LDS granule g of row r holds global granule g ^ ((r>>1)&3).
// + R9-proven XCD block swizzle (grids 192/256, %8==0).
// ---------------------------------------------------------------------------
template <bool RELU, typename OutT>
__global__ __launch_bounds__(512) void k_gemm256(
    const __bf16* __restrict__ A, const __bf16* __restrict__ BT,
    const float* __restrict__ bias, OutT* __restrict__ C,
    int M, int N, int K) {
  __shared__ __align__(16) __bf16 sA[4 * 8192];
  __shared__ __align__(16) __bf16 sB[4 * 8192];
  const int tid = threadIdx.x, lane = tid & 63, wv = tid >> 6;
  const int wm = wv >> 2, wn = wv & 3;
  const int lrow = lane & 15, hi = lane >> 4;
  const int nwg = gridDim.x * gridDim.y;
  const int flat = blockIdx.y * gridDim.x + blockIdx.x;
  const int cpx = nwg >> 3;
  const int swzb = (flat & 7) * cpx + (flat >> 3);
  const int m0 = (swzb / gridDim.x) * 256;
  const int n0 = (swzb % gridDim.x) * 256;
  const int NT = K >> 6;

  const int lsub = lane >> 2;                      // row within 16-row chunk
  const int gg = (lane & 3) ^ ((lane >> 3) & 3);   // swizzled source granule
  const int gr = hi ^ ((lrow >> 1) & 3);           // swizzled read granule

  f32x4 acc[8][4];
#pragma unroll
  for (int r = 0; r < 8; ++r)
#pragma unroll
    for (int c = 0; c < 4; ++c) acc[r][c] = f32x4{0.f, 0.f, 0.f, 0.f};

  auto stage = [&](int p) {
    const int tile = p >> 1;
    const int slot = (((tile & 1) * 2) + (p & 1)) * 8192;
    const int kcol = tile * 64 + (p & 1) * 32 + gg * 8;
#pragma unroll
    for (int i = 0; i < 2; ++i) {
      const int c = wv * 2 + i;
      gload_lds16(A + (size_t)(m0 + c * 16 + lsub) * K + kcol, &sA[slot + c * 512]);
      gload_lds16(BT + (size_t)(n0 + c * 16 + lsub) * K + kcol, &sB[slot + c * 512]);
    }
  };

  auto compute = [&](int p) {
    const int slot = ((((p >> 1) & 1) * 2) + (p & 1)) * 8192;
    bf16x8 af[8], bfv[4];
#pragma unroll
    for (int r = 0; r < 8; ++r)
      af[r] = *(const bf16x8*)&sA[slot + (wm * 128 + r * 16 + lrow) * 32 + gr * 8];
#pragma unroll
    for (int c = 0; c < 4; ++c)
      bfv[c] = *(const bf16x8*)&sB[slot + (wn * 64 + c * 16 + lrow) * 32 + gr * 8];
    __builtin_amdgcn_s_setprio(1);
#pragma unroll
    for (int r = 0; r < 8; ++r)
#pragma unroll
      for (int c = 0; c < 4; ++c)
        acc[r][c] = __builtin_amdgcn_mfma_f32_16x16x32_bf16(af[r], bfv[c],
                                                            acc[r][c], 0, 0, 0);
    __builtin_amdgcn_s_setprio(0);
  };

  stage(0); stage(1); stage(2);
  int p = 0;
  for (; p < 2 * NT - 3; ++p) {
    VMCNT8(); S_BARRIER(); SCHED_FENCE();
    stage(p + 3);
    compute(p);
  }
  VMCNT8(); S_BARRIER(); SCHED_FENCE(); compute(p); ++p;
  VMCNT4(); S_BARRIER(); SCHED_FENCE(); compute(p); ++p;
  VMCNT0(); S_BARRIER(); SCHED_FENCE(); compute(p);

#pragma unroll
  for (int r = 0; r < 8; ++r) {
    const int row = m0 + wm * 128 + r * 16 + hi * 4;
#pragma unroll
    for (int c = 0; c < 4; ++c) {
      const int col = n0 + wn * 64 + c * 16 + lrow;
      const float bb = bias[col];
#pragma unroll
      for (int j = 0; j < 4; ++j) {
        float v = acc[r][c][j] + bb;
        if (RELU) v = fmaxf(v, 0.f);
        C[(size_t)(row + j) * N + col] = (OutT)v;
      }
    }
  }
}

// ---------------------------------------------------------------------------
// bf16 MFMA GEMM (R9-verified: round-2 body + XCD swizzle, plain epilogue).
// BM=MF*32, BN=128, BK=64, 4 waves (2x2). Used for N=1024 GEMMs.
// ---------------------------------------------------------------------------
template <int MF, bool RELU, typename OutT>
__global__ __launch_bounds__(256) void k_gemm(
    const __bf16* __restrict__ A, const __bf16* __restrict__ BT,
    const float* __restrict__ bias, OutT* __restrict__ C, int M, int N, int K) {
  __shared__ __bf16 sA[MF * 32 * 64];
  __shared__ __bf16 sB[128 * 64];
  const int tid = threadIdx.x, lane = tid & 63, wv = tid >> 6;
  const int wm = wv >> 1, wn = wv & 1;
  const int lrow = lane & 15, hi = lane >> 4;
  const int nwg = gridDim.x * gridDim.y;
  const int flat = blockIdx.y * gridDim.x + blockIdx.x;
  const int cpx = nwg >> 3;
  const int swzb = (flat & 7) * cpx + (flat >> 3);
  const int m0 = (swzb / gridDim.x) * (MF * 32);
  const int n0 = (swzb % gridDim.x) * 128;
  const int srow = lane >> 3;
  const int scolE = ((lane & 7) ^ srow) * 8;
  const int swz = (lrow & 7) << 4;

  f32x4 acc[MF][4];
#pragma unroll
  for (int r = 0; r < MF; ++r)
#pragma unroll
    for (int c = 0; c < 4; ++c) acc[r][c] = f32x4{0.f, 0.f, 0.f, 0.f};

  for (int k0 = 0; k0 < K; k0 += 64) {
    __syncthreads();
#pragma unroll
    for (int rb = wv; rb < MF * 4; rb += 4) {
      const int row = rb * 8 + srow;
      gload_lds16(A + (size_t)(m0 + row) * K + k0 + scolE, &sA[rb * 512]);
    }
#pragma unroll
    for (int rb = wv; rb < 16; rb += 4) {
      const int row = rb * 8 + srow;
      gload_lds16(BT + (size_t)(n0 + row) * K + k0 + scolE, &sB[rb * 512]);
    }
    __syncthreads();
#pragma unroll
    for (int kc = 0; kc < 2; ++kc) {
      bf16x8 af[MF], bfr[4];
#pragma unroll
      for (int r = 0; r < MF; ++r) {
        const int row = wm * (MF * 16) + r * 16 + lrow;
        af[r] = *(const bf16x8*)((const char*)sA + row * 128 + ((kc * 64 + hi * 16) ^ swz));
      }
#pragma unroll
      for (int c = 0; c < 4; ++c) {
        const int row = wn * 64 + c * 16 + lrow;
        bfr[c] = *(const bf16x8*)((const char*)sB + row * 128 + ((kc * 64 + hi * 16) ^ swz));
      }
#pragma unroll
      for (int r = 0; r < MF; ++r)
#pragma unroll
        for (int c = 0; c < 4; ++c)
          acc[r][c] = __builtin_amdgcn_mfma_f32_16x16x32_bf16(af[r], bfr[c],
                                                              acc[r][c], 0, 0, 0);
    }
  }

#pragma unroll
  for (int r = 0; r < MF; ++r) {
    const int row = m0 + wm * (MF * 16) + r * 16 + hi * 4;
#pragma unroll
    for (int c = 0; c < 4; ++c) {
      const int col = n0 + wn * 64 + c * 16 + lrow;
      const float bb = bias[col];
#pragma unroll
      for (int j = 0; j < 4; ++j) {
        float v = acc[r][c][j] + bb;
        if (RELU) v = fmaxf(v, 0.f);
        C[(size_t)(row + j) * N + col] = (OutT)v;
      }
    }
  }
}

// ---------------------------------------------------------------------------
// Flash attention — R15-verified (builtin MFMAs, KVBLK=64, double-buffered
// issue-early staging). Unchanged this round.
// ---------------------------------------------------------------------------
__global__ __launch_bounds__(256) void k_attn(
    const __bf16* __restrict__ qkv, const __bf16* __restrict__ vT,
    const float* __restrict__ mask, __bf16* __restrict__ out) {
  const int qb = blockIdx.x, h = blockIdx.y, b = blockIdx.z;
  const int tid = threadIdx.x, lane = tid & 63, wv = tid >> 6;
  const int lrow = lane & 15, hi = lane >> 4;

  __shared__ __bf16 sK[2][64 * 64];  // [buf][key][d], swizzled
  __shared__ __bf16 sV[2][64 * 64];  // [buf][d][key], swizzled

  const size_t base = (size_t)b * SEQ * 3072;
  const __bf16* Qb = qkv + base + h * 64;
  const __bf16* Kb = qkv + base + 1024 + h * 64;
  const __bf16* vTb = vT + ((size_t)b * 1024 + h * 64) * SEQ;
  const float* maskb = mask + (size_t)b * SEQ;

  const int q0 = qb * 64 + wv * 16;
  const bf16x8 qf0 = *(const bf16x8*)&Qb[(size_t)(q0 + lrow) * 3072 + hi * 8];
  const bf16x8 qf1 = *(const bf16x8*)&Qb[(size_t)(q0 + lrow) * 3072 + 32 + hi * 8];

  float m_r = -3e38f, l_r = 0.f;
  f32x4 o[4];
#pragma unroll
  for (int d = 0; d < 4; ++d) o[d] = f32x4{0.f, 0.f, 0.f, 0.f};

  const int srow = lane >> 3;
  const int scolE = ((lane & 7) ^ srow) * 8;
  const int swz = (lrow & 7) << 4;

  auto stage = [&](int t) {
    const int k0s = t * 64;
    __bf16* dK = sK[t & 1];
    __bf16* dV = sV[t & 1];
#pragma unroll
    for (int r = 0; r < 2; ++r) {
      const int rb = r * 4 + wv;
      const int row = rb * 8 + srow;
      gload_lds16(Kb + (size_t)(k0s + row) * 3072 + scolE, &dK[rb * 512]);
      gload_lds16(vTb + (size_t)row * SEQ + k0s + scolE, &dV[rb * 512]);
    }
  };

  stage(0);
  const int NT = SEQ / 64;
  for (int t = 0; t < NT; ++t) {
    __syncthreads();  // drains vmcnt+lgkmcnt: stage(t) landed block-wide
    if (t + 1 < NT) stage(t + 1);  // in flight through compute(t)
    const __bf16* cK = sK[t & 1];
    const __bf16* cV = sV[t & 1];
    const int k0 = t * 64;

    // S^T = K * Q^T : st[t4][j] = S[key = t4*16 + 4hi + j][q = lrow]
    f32x4 st[4];
#pragma unroll
    for (int t4 = 0; t4 < 4; ++t4) {
      const char* rp = (const char*)cK + (t4 * 16 + lrow) * 128;
      const bf16x8 ka = *(const bf16x8*)(rp + ((hi * 16) ^ swz));
      const bf16x8 kb = *(const bf16x8*)(rp + ((64 + hi * 16) ^ swz));
      f32x4 a = f32x4{0.f, 0.f, 0.f, 0.f};
      a = __builtin_amdgcn_mfma_f32_16x16x32_bf16(ka, qf0, a, 0, 0, 0);
      a = __builtin_amdgcn_mfma_f32_16x16x32_bf16(kb, qf1, a, 0, 0, 0);
      st[t4] = a;
    }

    float pm = -3e38f;
#pragma unroll
    for (int t4 = 0; t4 < 4; ++t4) {
      const f32x4 mk = *(const f32x4*)&maskb[k0 + t4 * 16 + hi * 4];
#pragma unroll
      for (int j = 0; j < 4; ++j) {
        st[t4][j] = st[t4][j] * 0.125f + mk[j];
        pm = fmaxf(pm, st[t4][j]);
      }
    }
    pm = fmaxf(pm, __shfl_xor(pm, 16));
    pm = fmaxf(pm, __shfl_xor(pm, 32));

    const float mn = fmaxf(m_r, pm);
    const float so = __expf(m_r - mn);
    m_r = mn;
    float rs = 0.f;
#pragma unroll
    for (int t4 = 0; t4 < 4; ++t4)
#pragma unroll
      for (int j = 0; j < 4; ++j) {
        st[t4][j] = __expf(st[t4][j] - mn);
        rs += st[t4][j];
      }
    rs += __shfl_xor(rs, 16);
    rs += __shfl_xor(rs, 32);
    l_r = l_r * so + rs;

    float so_o[4];
#pragma unroll
    for (int jj = 0; jj < 4; ++jj) so_o[jj] = __shfl(so, hi * 4 + jj);
#pragma unroll
    for (int d = 0; d < 4; ++d)
#pragma unroll
      for (int jj = 0; jj < 4; ++jj) o[d][jj] *= so_o[jj];

    // P -> bf16 A-frags of 16x16x16 (k = 4hi+j), as <4 x i16> for the builtin
    s16x4 pa[4];
#pragma unroll
    for (int t4 = 0; t4 < 4; ++t4)
#pragma unroll
      for (int j = 0; j < 4; ++j) {
        const __bf16 pb = (__bf16)st[t4][j];
        pa[t4][j] = __builtin_bit_cast(short, pb);
      }

#pragma unroll
    for (int d = 0; d < 4; ++d) {
      const char* rp = (const char*)cV + (d * 16 + lrow) * 128;
#pragma unroll
      for (int t4 = 0; t4 < 4; ++t4) {
        const s16x4 vb = *(const s16x4*)(rp + ((t4 * 32 + hi * 8) ^ swz));
        o[d] = __builtin_amdgcn_mfma_f32_16x16x16bf16_1k(pa[t4], vb, o[d], 0, 0, 0);
      }
    }
  }

  __syncthreads();
  float linv[4];
#pragma unroll
  for (int jj = 0; jj < 4; ++jj) linv[jj] = 1.0f / __shfl(l_r, hi * 4 + jj);
#pragma unroll
  for (int d = 0; d < 4; ++d)
#pragma unroll
    for (int jj = 0; jj < 4; ++jj)
      out[((size_t)b * SEQ + q0 + hi * 4 + jj) * DMODEL + h * 64 + d * 16 + lrow] =
          (__bf16)(o[d][jj] * linv[jj]);
}

// ---------------------------------------------------------------------------
// out = LayerNorm(x + y) * g + beta ; writes fp32 residual and optional bf16
// ---------------------------------------------------------------------------
__global__ __launch_bounds__(256) void k_add_ln(
    const float* __restrict__ x, const float* __restrict__ y,
    const float* __restrict__ g, const float* __restrict__ be,
    float* __restrict__ of, __bf16* __restrict__ ob) {
  const int row = blockIdx.x, tid = threadIdx.x;
  const float4 a = ((const float4*)(x + (size_t)row * 1024))[tid];
  const float4 b = ((const float4*)(y + (size_t)row * 1024))[tid];
  const float v0 = a.x + b.x, v1 = a.y + b.y, v2 = a.z + b.z, v3 = a.w + b.w;
  float s = v0 + v1 + v2 + v3;
  float s2 = v0 * v0 + v1 * v1 + v2 * v2 + v3 * v3;
#pragma unroll
  for (int off = 32; off > 0; off >>= 1) {
    s += __shfl_xor(s, off);
    s2 += __shfl_xor(s2, off);
  }
  __shared__ float red[2][4];
  const int wv = tid >> 6, lane = tid & 63;
  if (lane == 0) { red[0][wv] = s; red[1][wv] = s2; }
  __syncthreads();
  s = red[0][0] + red[0][1] + red[0][2] + red[0][3];
  s2 = red[1][0] + red[1][1] + red[1][2] + red[1][3];
  const float mean = s * (1.0f / 1024.0f);
  const float var = s2 * (1.0f / 1024.0f) - mean * mean;
  const float rstd = rsqrtf(var + 1e-5f);
  const float4 gg = ((const float4*)g)[tid];
  const float4 bt = ((const float4*)be)[tid];
  float4 r;
  r.x = (v0 - mean) * rstd * gg.x + bt.x;
  r.y = (v1 - mean) * rstd * gg.y + bt.y;
  r.z = (v2 - mean) * rstd * gg.z + bt.z;
  r.w = (v3 - mean) * rstd * gg.w + bt.w;
  ((float4*)(of + (size_t)row * 1024))[tid] = r;
  if (ob) {
    bf16x4 rb;
    rb[0] = (__bf16)r.x; rb[1] = (__bf16)r.y; rb[2] = (__bf16)r.z; rb[3] = (__bf16)r.w;
    *(bf16x4*)(ob + (size_t)row * 1024 + tid * 4) = rb;
  }
}

// ---------------------------------------------------------------------------
extern "C" void kernel_launch(void* const* d_in, const int* in_sizes, int n_in,
                              void* d_out, int out_size, void* d_ws, size_t ws_size,
                              hipStream_t stream) {
  const float* x = (const float*)d_in[0];
  const float* src_mask = (const float*)d_in[1];
  const float* w_q = (const float*)d_in[2];
  const float* b_q = (const float*)d_in[3];
  const float* w_k = (const float*)d_in[4];
  const float* b_k = (const float*)d_in[5];
  const float* w_v = (const float*)d_in[6];
  const float* b_v = (const float*)d_in[7];
  const float* w_o = (const float*)d_in[8];
  const float* b_o = (const float*)d_in[9];
  const float* w_ff1 = (const float*)d_in[10];
  const float* b_ff1 = (const float*)d_in[11];
  const float* w_ff2 = (const float*)d_in[12];
  const float* b_ff2 = (const float*)d_in[13];
  const float* ln1_g = (const float*)d_in[14];
  const float* ln1_b = (const float*)d_in[15];
  const float* ln2_g = (const float*)d_in[16];
  const float* ln2_b = (const float*)d_in[17];

  char* ws = (char*)d_ws;
  constexpr size_t O_WQKVT = 0;                               // 3072x1024 bf16
  constexpr size_t O_WOT = O_WQKVT + 3072ull * 1024 * 2;      // 1024x1024 bf16
  constexpr size_t O_WFF1T = O_WOT + 1024ull * 1024 * 2;      // 4096x1024 bf16
  constexpr size_t O_WFF2T = O_WFF1T + 4096ull * 1024 * 2;    // 1024x4096 bf16
  constexpr size_t O_BQKV = O_WFF2T + 4096ull * 1024 * 2;     // 3072 f32
  constexpr size_t O_XBF = O_BQKV + 3072ull * 4;              // 4096x1024 bf16
  constexpr size_t O_QKV = O_XBF + 4096ull * 1024 * 2;        // 4096x3072 bf16
  constexpr size_t O_ATTN = O_QKV + 4096ull * 3072 * 2;       // 4096x1024 bf16
  constexpr size_t O_PROJ = O_ATTN + 4096ull * 1024 * 2;      // 4096x1024 f32
  constexpr size_t O_H1F = O_PROJ + 4096ull * 1024 * 4;       // 4096x1024 f32
  constexpr size_t O_H1B = O_H1F + 4096ull * 1024 * 4;        // 4096x1024 bf16
  constexpr size_t O_VT = O_PROJ;   // 2x1024x2048 bf16 (dead before proj)
  constexpr size_t O_FF = O_QKV;    // 4096x4096 bf16 (reuse)
  constexpr size_t O_FF2 = O_PROJ;  // 4096x1024 f32 (reuse, after ln1)

  __bf16* wqkvT = (__bf16*)(ws + O_WQKVT);
  __bf16* woT = (__bf16*)(ws + O_WOT);
  __bf16* wff1T = (__bf16*)(ws + O_WFF1T);
  __bf16* wff2T = (__bf16*)(ws + O_WFF2T);
  float* bqkv = (float*)(ws + O_BQKV);
  __bf16* xbf = (__bf16*)(ws + O_XBF);
  __bf16* qkvb = (__bf16*)(ws + O_QKV);
  __bf16* attnb = (__bf16*)(ws + O_ATTN);
  float* proj = (float*)(ws + O_PROJ);
  float* h1f = (float*)(ws + O_H1F);
  __bf16* h1b = (__bf16*)(ws + O_H1B);
  __bf16* vT = (__bf16*)(ws + O_VT);
  __bf16* ffb = (__bf16*)(ws + O_FF);
  float* ff2 = (float*)(ws + O_FF2);

  // weight prep
  k_transpose_to_bf16<<<dim3(32, 32), 256, 0, stream>>>(w_q, wqkvT, 1024, 1024);
  k_transpose_to_bf16<<<dim3(32, 32), 256, 0, stream>>>(w_k, wqkvT + 1024 * 1024, 1024, 1024);
  k_transpose_to_bf16<<<dim3(32, 32), 256, 0, stream>>>(w_v, wqkvT + 2 * 1024 * 1024, 1024, 1024);
  k_transpose_to_bf16<<<dim3(32, 32), 256, 0, stream>>>(w_o, woT, 1024, 1024);
  k_transpose_to_bf16<<<dim3(128, 32), 256, 0, stream>>>(w_ff1, wff1T, 1024, 4096);
  k_transpose_to_bf16<<<dim3(32, 128), 256, 0, stream>>>(w_ff2, wff2T, 4096, 1024);
  k_concat3<<<12, 256, 0, stream>>>(b_q, b_k, b_v, bqkv);
  k_cvt_bf16<<<4096, 256, 0, stream>>>(x, xbf, MTOT * DMODEL);

  // fused QKV projection (256^2 counted-vmcnt pipeline)
  k_gemm256<false, __bf16><<<dim3(12, 16), 512, 0, stream>>>(xbf, wqkvT, bqkv, qkvb,
                                                             MTOT, 3072, 1024);
  // V transpose for attention B-frags
  k_transpose_v<<<dim3(64, 32, 2), 256, 0, stream>>>(qkvb, vT);
  // attention (R15-verified)
  k_attn<<<dim3(SEQ / 64, NHEAD, BATCH), 256, 0, stream>>>(qkvb, vT, src_mask, attnb);
  // output projection (f32)
  k_gemm<2, false, float><<<dim3(8, 64), 256, 0, stream>>>(attnb, woT, b_o, proj,
                                                           MTOT, 1024, 1024);
  // ln1
  k_add_ln<<<4096, 256, 0, stream>>>(x, proj, ln1_g, ln1_b, h1f, h1b);
  // ff1 + relu (256^2 counted-vmcnt pipeline)
  k_gemm256<true, __bf16><<<dim3(16, 16), 512, 0, stream>>>(h1b, wff1T, b_ff1, ffb,
                                                            MTOT, DFF, 1024);
  // ff2
  k_gemm<2, false, float><<<dim3(8, 64), 256, 0, stream>>>(ffb, wff2T, b_ff2, ff2,
                                                           MTOT, 1024, DFF);
  // ln2 -> d_out
  k_add_ln<<<4096, 256, 0, stream>>>(h1f, ff2, ln2_g, ln2_b, (float*)d_out, nullptr);
}

// Round 17
// 274.806 us; speedup vs baseline: 1.0738x; 1.0085x over previous
//
#include <hip/hip_runtime.h>
#include <cstdint>
#include <cstddef>

#define BATCH 2
#define SEQ 2048
#define DMODEL 1024
#define NHEAD 16
#define DFF 4096
#define MTOT (BATCH * SEQ) /* 4096 */

typedef __bf16 bf16x8 __attribute__((ext_vector_type(8)));
typedef __bf16 bf16x4 __attribute__((ext_vector_type(4)));
typedef short s16x4 __attribute__((ext_vector_type(4)));
typedef float f32x4 __attribute__((ext_vector_type(4)));

#define S_BARRIER() __builtin_amdgcn_s_barrier()
#define SCHED_FENCE() __builtin_amdgcn_sched_barrier(0)
#define VMCNT8() asm volatile("s_waitcnt vmcnt(8)" ::: "memory")
#define VMCNT4() asm volatile("s_waitcnt vmcnt(4)" ::: "memory")
#define VMCNT0() asm volatile("s_waitcnt vmcnt(0)" ::: "memory")

// async global->LDS, 16B/lane; LDS dest = wave-uniform base + lane*16 (m104).
__device__ __forceinline__ void gload_lds16(const void* g, void* l) {
  __builtin_amdgcn_global_load_lds(
      (__attribute__((address_space(1))) void*)(uintptr_t)g,
      (__attribute__((address_space(3))) void*)(uint32_t)(uintptr_t)l,
      16, 0, 0);
}

// ---------------------------------------------------------------------------
// fp32 [K,N] -> bf16 [N,K] transpose (weights -> B^T layout)
// ---------------------------------------------------------------------------
__global__ __launch_bounds__(256) void k_transpose_to_bf16(
    const float* __restrict__ w, __bf16* __restrict__ wt, int K, int N) {
  __shared__ float t[32][33];
  const int n0 = blockIdx.x * 32, k0 = blockIdx.y * 32;
  const int tx = threadIdx.x & 31, ty = threadIdx.x >> 5;
#pragma unroll
  for (int i = ty; i < 32; i += 8) t[i][tx] = w[(size_t)(k0 + i) * N + n0 + tx];
  __syncthreads();
#pragma unroll
  for (int i = ty; i < 32; i += 8)
    wt[(size_t)(n0 + i) * K + k0 + tx] = (__bf16)t[tx][i];
}

__global__ __launch_bounds__(256) void k_cvt_bf16(
    const float* __restrict__ in, __bf16* __restrict__ out, int n) {
  const int i = (blockIdx.x * 256 + threadIdx.x) * 4;
  if (i >= n) return;
  const float4 v = *(const float4*)(in + i);
  bf16x4 r;
  r[0] = (__bf16)v.x; r[1] = (__bf16)v.y; r[2] = (__bf16)v.z; r[3] = (__bf16)v.w;
  *(bf16x4*)(out + i) = r;
}

__global__ void k_concat3(const float* __restrict__ a, const float* __restrict__ b,
                          const float* __restrict__ c, float* __restrict__ o) {
  const int i = blockIdx.x * 256 + threadIdx.x;
  if (i >= 3072) return;
  o[i] = (i < 1024) ? a[i] : (i < 2048) ? b[i - 1024] : c[i - 2048];
}

// mask * log2(e) for exp2-domain softmax
__global__ void k_scale_mask(const float* __restrict__ in, float* __restrict__ o, int n) {
  const int i = blockIdx.x * 256 + threadIdx.x;
  if (i < n) o[i] = in[i] * 1.44269504f;
}

// bf16 V-section transpose: qkvb[b*S+s][2048+c] -> vT[b*1024+c][s]
__global__ __launch_bounds__(256) void k_transpose_v(
    const __bf16* __restrict__ qkvb, __bf16* __restrict__ vT) {
  __shared__ __bf16 t[32][33];
  const int s0 = blockIdx.x * 32, c0 = blockIdx.y * 32, b = blockIdx.z;
  const int tx = threadIdx.x & 31, ty = threadIdx.x >> 5;
#pragma unroll
  for (int i = ty; i < 32; i += 8)
    t[i][tx] = qkvb[(size_t)(b * SEQ + s0 + i) * 3072 + 2048 + c0 + tx];
  __syncthreads();
#pragma unroll
  for (int i = ty; i < 32; i += 8)
    vT[((size_t)b * 1024 + c0 + i) * SEQ + s0 + tx] = t[tx][i];
}

// ---------------------------------------------------------------------------
// 256x256 deep-pipelined MFMA GEMM (T3+T4 counted-vmcnt, ALL-BUILTIN MFMAs).
// R16-verified. 512 thr = 8 waves (2M x 4N); wave owns 128x64.
// ---------------------------------------------------------------------------
template <bool RELU, typename OutT>
__global__ __launch_bounds__(512) void k_gemm256(
    const __bf16* __restrict__ A, const __bf16* __restrict__ BT,
    const float* __restrict__ bias, OutT* __restrict__ C,
    int M, int N, int K) {
  __shared__ __align__(16) __bf16 sA[4 * 8192];
  __shared__ __align__(16) __bf16 sB[4 * 8192];
  const int tid = threadIdx.x, lane = tid & 63, wv = tid >> 6;
  const int wm = wv >> 2, wn = wv & 3;
  const int lrow = lane & 15, hi = lane >> 4;
  const int nwg = gridDim.x * gridDim.y;
  const int flat = blockIdx.y * gridDim.x + blockIdx.x;
  const int cpx = nwg >> 3;
  const int swzb = (flat & 7) * cpx + (flat >> 3);
  const int m0 = (swzb / gridDim.x) * 256;
  const int n0 = (swzb % gridDim.x) * 256;
  const int NT = K >> 6;

  const int lsub = lane >> 2;
  const int gg = (lane & 3) ^ ((lane >> 3) & 3);
  const int gr = hi ^ ((lrow >> 1) & 3);

  f32x4 acc[8][4];
#pragma unroll
  for (int r = 0; r < 8; ++r)
#pragma unroll
    for (int c = 0; c < 4; ++c) acc[r][c] = f32x4{0.f, 0.f, 0.f, 0.f};

  auto stage = [&](int p) {
    const int tile = p >> 1;
    const int slot = (((tile & 1) * 2) + (p & 1)) * 8192;
    const int kcol = tile * 64 + (p & 1) * 32 + gg * 8;
#pragma unroll
    for (int i = 0; i < 2; ++i) {
      const int c = wv * 2 + i;
      gload_lds16(A + (size_t)(m0 + c * 16 + lsub) * K + kcol, &sA[slot + c * 512]);
      gload_lds16(BT + (size_t)(n0 + c * 16 + lsub) * K + kcol, &sB[slot + c * 512]);
    }
  };

  auto compute = [&](int p) {
    const int slot = ((((p >> 1) & 1) * 2) + (p & 1)) * 8192;
    bf16x8 af[8], bfv[4];
#pragma unroll
    for (int r = 0; r < 8; ++r)
      af[r] = *(const bf16x8*)&sA[slot + (wm * 128 + r * 16 + lrow) * 32 + gr * 8];
#pragma unroll
    for (int c = 0; c < 4; ++c)
      bfv[c] = *(const bf16x8*)&sB[slot + (wn * 64 + c * 16 + lrow) * 32 + gr * 8];
    __builtin_amdgcn_s_setprio(1);
#pragma unroll
    for (int r = 0; r < 8; ++r)
#pragma unroll
      for (int c = 0; c < 4; ++c)
        acc[r][c] = __builtin_amdgcn_mfma_f32_16x16x32_bf16(af[r], bfv[c],
                                                            acc[r][c], 0, 0, 0);
    __builtin_amdgcn_s_setprio(0);
  };

  stage(0); stage(1); stage(2);
  int p = 0;
  for (; p < 2 * NT - 3; ++p) {
    VMCNT8(); S_BARRIER(); SCHED_FENCE();
    stage(p + 3);
    compute(p);
  }
  VMCNT8(); S_BARRIER(); SCHED_FENCE(); compute(p); ++p;
  VMCNT4(); S_BARRIER(); SCHED_FENCE(); compute(p); ++p;
  VMCNT0(); S_BARRIER(); SCHED_FENCE(); compute(p);

#pragma unroll
  for (int r = 0; r < 8; ++r) {
    const int row = m0 + wm * 128 + r * 16 + hi * 4;
#pragma unroll
    for (int c = 0; c < 4; ++c) {
      const int col = n0 + wn * 64 + c * 16 + lrow;
      const float bb = bias[col];
#pragma unroll
      for (int j = 0; j < 4; ++j) {
        float v = acc[r][c][j] + bb;
        if (RELU) v = fmaxf(v, 0.f);
        C[(size_t)(row + j) * N + col] = (OutT)v;
      }
    }
  }
}

// ---------------------------------------------------------------------------
// bf16 MFMA GEMM (R9-verified: round-2 body + XCD swizzle, plain epilogue).
// BM=MF*32, BN=128, BK=64, 4 waves (2x2). Used for N=1024 GEMMs.
// ---------------------------------------------------------------------------
template <int MF, bool RELU, typename OutT>
__global__ __launch_bounds__(256) void k_gemm(
    const __bf16* __restrict__ A, const __bf16* __restrict__ BT,
    const float* __restrict__ bias, OutT* __restrict__ C, int M, int N, int K) {
  __shared__ __bf16 sA[MF * 32 * 64];
  __shared__ __bf16 sB[128 * 64];
  const int tid = threadIdx.x, lane = tid & 63, wv = tid >> 6;
  const int wm = wv >> 1, wn = wv & 1;
  const int lrow = lane & 15, hi = lane >> 4;
  const int nwg = gridDim.x * gridDim.y;
  const int flat = blockIdx.y * gridDim.x + blockIdx.x;
  const int cpx = nwg >> 3;
  const int swzb = (flat & 7) * cpx + (flat >> 3);
  const int m0 = (swzb / gridDim.x) * (MF * 32);
  const int n0 = (swzb % gridDim.x) * 128;
  const int srow = lane >> 3;
  const int scolE = ((lane & 7) ^ srow) * 8;
  const int swz = (lrow & 7) << 4;

  f32x4 acc[MF][4];
#pragma unroll
  for (int r = 0; r < MF; ++r)
#pragma unroll
    for (int c = 0; c < 4; ++c) acc[r][c] = f32x4{0.f, 0.f, 0.f, 0.f};

  for (int k0 = 0; k0 < K; k0 += 64) {
    __syncthreads();
#pragma unroll
    for (int rb = wv; rb < MF * 4; rb += 4) {
      const int row = rb * 8 + srow;
      gload_lds16(A + (size_t)(m0 + row) * K + k0 + scolE, &sA[rb * 512]);
    }
#pragma unroll
    for (int rb = wv; rb < 16; rb += 4) {
      const int row = rb * 8 + srow;
      gload_lds16(BT + (size_t)(n0 + row) * K + k0 + scolE, &sB[rb * 512]);
    }
    __syncthreads();
#pragma unroll
    for (int kc = 0; kc < 2; ++kc) {
      bf16x8 af[MF], bfr[4];
#pragma unroll
      for (int r = 0; r < MF; ++r) {
        const int row = wm * (MF * 16) + r * 16 + lrow;
        af[r] = *(const bf16x8*)((const char*)sA + row * 128 + ((kc * 64 + hi * 16) ^ swz));
      }
#pragma unroll
      for (int c = 0; c < 4; ++c) {
        const int row = wn * 64 + c * 16 + lrow;
        bfr[c] = *(const bf16x8*)((const char*)sB + row * 128 + ((kc * 64 + hi * 16) ^ swz));
      }
#pragma unroll
      for (int r = 0; r < MF; ++r)
#pragma unroll
        for (int c = 0; c < 4; ++c)
          acc[r][c] = __builtin_amdgcn_mfma_f32_16x16x32_bf16(af[r], bfr[c],
                                                              acc[r][c], 0, 0, 0);
    }
  }

#pragma unroll
  for (int r = 0; r < MF; ++r) {
    const int row = m0 + wm * (MF * 16) + r * 16 + hi * 4;
#pragma unroll
    for (int c = 0; c < 4; ++c) {
      const int col = n0 + wn * 64 + c * 16 + lrow;
      const float bb = bias[col];
#pragma unroll
      for (int j = 0; j < 4; ++j) {
        float v = acc[r][c][j] + bb;
        if (RELU) v = fmaxf(v, 0.f);
        C[(size_t)(row + j) * N + col] = (OutT)v;
      }
    }
  }
}

// ---------------------------------------------------------------------------
// Flash attention — R15-verified structure (builtin MFMAs, KVBLK=64, dbuf
// issue-early staging). This round's delta is numerics-only in the softmax:
// (1) exp2-domain (mask pre-scaled by log2e; scale folded into the fmac;
//     __builtin_amdgcn_exp2f — removes the hidden v_mul inside __expf);
// (2) T13 defer-max: skip o-rescale while pm <= m_r + 11.5 (=8*log2e);
//     P bounded by 2^11.5~2900, safe in bf16/f32 accumulate (HK THR=8).
// ---------------------------------------------------------------------------
__global__ __launch_bounds__(256) void k_attn(
    const __bf16* __restrict__ qkv, const __bf16* __restrict__ vT,
    const float* __restrict__ mask2, __bf16* __restrict__ out) {
  const int qb = blockIdx.x, h = blockIdx.y, b = blockIdx.z;
  const int tid = threadIdx.x, lane = tid & 63, wv = tid >> 6;
  const int lrow = lane & 15, hi = lane >> 4;

  __shared__ __bf16 sK[2][64 * 64];  // [buf][key][d], swizzled
  __shared__ __bf16 sV[2][64 * 64];  // [buf][d][key], swizzled

  const size_t base = (size_t)b * SEQ * 3072;
  const __bf16* Qb = qkv + base + h * 64;
  const __bf16* Kb = qkv + base + 1024 + h * 64;
  const __bf16* vTb = vT + ((size_t)b * 1024 + h * 64) * SEQ;
  const float* maskb = mask2 + (size_t)b * SEQ;

  const int q0 = qb * 64 + wv * 16;
  const bf16x8 qf0 = *(const bf16x8*)&Qb[(size_t)(q0 + lrow) * 3072 + hi * 8];
  const bf16x8 qf1 = *(const bf16x8*)&Qb[(size_t)(q0 + lrow) * 3072 + 32 + hi * 8];

  float m_r = -3e38f, l_r = 0.f;
  f32x4 o[4];
#pragma unroll
  for (int d = 0; d < 4; ++d) o[d] = f32x4{0.f, 0.f, 0.f, 0.f};

  const int srow = lane >> 3;
  const int scolE = ((lane & 7) ^ srow) * 8;
  const int swz = (lrow & 7) << 4;

  auto stage = [&](int t) {
    const int k0s = t * 64;
    __bf16* dK = sK[t & 1];
    __bf16* dV = sV[t & 1];
#pragma unroll
    for (int r = 0; r < 2; ++r) {
      const int rb = r * 4 + wv;
      const int row = rb * 8 + srow;
      gload_lds16(Kb + (size_t)(k0s + row) * 3072 + scolE, &dK[rb * 512]);
      gload_lds16(vTb + (size_t)row * SEQ + k0s + scolE, &dV[rb * 512]);
    }
  };

  stage(0);
  const int NT = SEQ / 64;
  for (int t = 0; t < NT; ++t) {
    __syncthreads();  // drains vmcnt+lgkmcnt: stage(t) landed block-wide
    if (t + 1 < NT) stage(t + 1);  // in flight through compute(t)
    const __bf16* cK = sK[t & 1];
    const __bf16* cV = sV[t & 1];
    const int k0 = t * 64;

    // S^T = K * Q^T : st[t4][j] = S[key = t4*16 + 4hi + j][q = lrow]
    f32x4 st[4];
#pragma unroll
    for (int t4 = 0; t4 < 4; ++t4) {
      const char* rp = (const char*)cK + (t4 * 16 + lrow) * 128;
      const bf16x8 ka = *(const bf16x8*)(rp + ((hi * 16) ^ swz));
      const bf16x8 kb = *(const bf16x8*)(rp + ((64 + hi * 16) ^ swz));
      f32x4 a = f32x4{0.f, 0.f, 0.f, 0.f};
      a = __builtin_amdgcn_mfma_f32_16x16x32_bf16(ka, qf0, a, 0, 0, 0);
      a = __builtin_amdgcn_mfma_f32_16x16x32_bf16(kb, qf1, a, 0, 0, 0);
      st[t4] = a;
    }

    // exp2-domain logits: st*0.125*log2e + mask2
    float pm = -3e38f;
#pragma unroll
    for (int t4 = 0; t4 < 4; ++t4) {
      const f32x4 mk = *(const f32x4*)&maskb[k0 + t4 * 16 + hi * 4];
#pragma unroll
      for (int j = 0; j < 4; ++j) {
        st[t4][j] = st[t4][j] * 0.18033688f + mk[j];
        pm = fmaxf(pm, st[t4][j]);
      }
    }
    pm = fmaxf(pm, __shfl_xor(pm, 16));
    pm = fmaxf(pm, __shfl_xor(pm, 32));

    // T13 defer-max: only rescale when the running max grew materially
    if (__any(pm > m_r + 11.5f)) {
      const float mn = fmaxf(m_r, pm);
      const float so = __builtin_amdgcn_exp2f(m_r - mn);
      m_r = mn;
      l_r *= so;
      float so_o[4];
#pragma unroll
      for (int jj = 0; jj < 4; ++jj) so_o[jj] = __shfl(so, hi * 4 + jj);
#pragma unroll
      for (int d = 0; d < 4; ++d)
#pragma unroll
        for (int jj = 0; jj < 4; ++jj) o[d][jj] *= so_o[jj];
    }

    float rs = 0.f;
#pragma unroll
    for (int t4 = 0; t4 < 4; ++t4)
#pragma unroll
      for (int j = 0; j < 4; ++j) {
        st[t4][j] = __builtin_amdgcn_exp2f(st[t4][j] - m_r);
        rs += st[t4][j];
      }
    rs += __shfl_xor(rs, 16);
    rs += __shfl_xor(rs, 32);
    l_r += rs;

    // P -> bf16 A-frags of 16x16x16 (k = 4hi+j), as <4 x i16> for the builtin
    s16x4 pa[4];
#pragma unroll
    for (int t4 = 0; t4 < 4; ++t4)
#pragma unroll
      for (int j = 0; j < 4; ++j) {
        const __bf16 pb = (__bf16)st[t4][j];
        pa[t4][j] = __builtin_bit_cast(short, pb);
      }

#pragma unroll
    for (int d = 0; d < 4; ++d) {
      const char* rp = (const char*)cV + (d * 16 + lrow) * 128;
#pragma unroll
      for (int t4 = 0; t4 < 4; ++t4) {
        const s16x4 vb = *(const s16x4*)(rp + ((t4 * 32 + hi * 8) ^ swz));
        o[d] = __builtin_amdgcn_mfma_f32_16x16x16bf16_1k(pa[t4], vb, o[d], 0, 0, 0);
      }
    }
  }

  __syncthreads();
  float linv[4];
#pragma unroll
  for (int jj = 0; jj < 4; ++jj) linv[jj] = 1.0f / __shfl(l_r, hi * 4 + jj);
#pragma unroll
  for (int d = 0; d < 4; ++d)
#pragma unroll
    for (int jj = 0; jj < 4; ++jj)
      out[((size_t)b * SEQ + q0 + hi * 4 + jj) * DMODEL + h * 64 + d * 16 + lrow] =
          (__bf16)(o[d][jj] * linv[jj]);
}

// ---------------------------------------------------------------------------
// out = LayerNorm(x + y) * g + beta ; writes fp32 residual and optional bf16
// ---------------------------------------------------------------------------
__global__ __launch_bounds__(256) void k_add_ln(
    const float* __restrict__ x, const float* __restrict__ y,
    const float* __restrict__ g, const float* __restrict__ be,
    float* __restrict__ of, __bf16* __restrict__ ob) {
  const int row = blockIdx.x, tid = threadIdx.x;
  const float4 a = ((const float4*)(x + (size_t)row * 1024))[tid];
  const float4 b = ((const float4*)(y + (size_t)row * 1024))[tid];
  const float v0 = a.x + b.x, v1 = a.y + b.y, v2 = a.z + b.z, v3 = a.w + b.w;
  float s = v0 + v1 + v2 + v3;
  float s2 = v0 * v0 + v1 * v1 + v2 * v2 + v3 * v3;
#pragma unroll
  for (int off = 32; off > 0; off >>= 1) {
    s += __shfl_xor(s, off);
    s2 += __shfl_xor(s2, off);
  }
  __shared__ float red[2][4];
  const int wv = tid >> 6, lane = tid & 63;
  if (lane == 0) { red[0][wv] = s; red[1][wv] = s2; }
  __syncthreads();
  s = red[0][0] + red[0][1] + red[0][2] + red[0][3];
  s2 = red[1][0] + red[1][1] + red[1][2] + red[1][3];
  const float mean = s * (1.0f / 1024.0f);
  const float var = s2 * (1.0f / 1024.0f) - mean * mean;
  const float rstd = rsqrtf(var + 1e-5f);
  const float4 gg = ((const float4*)g)[tid];
  const float4 bt = ((const float4*)be)[tid];
  float4 r;
  r.x = (v0 - mean) * rstd * gg.x + bt.x;
  r.y = (v1 - mean) * rstd * gg.y + bt.y;
  r.z = (v2 - mean) * rstd * gg.z + bt.z;
  r.w = (v3 - mean) * rstd * gg.w + bt.w;
  ((float4*)(of + (size_t)row * 1024))[tid] = r;
  if (ob) {
    bf16x4 rb;
    rb[0] = (__bf16)r.x; rb[1] = (__bf16)r.y; rb[2] = (__bf16)r.z; rb[3] = (__bf16)r.w;
    *(bf16x4*)(ob + (size_t)row * 1024 + tid * 4) = rb;
  }
}

// ---------------------------------------------------------------------------
extern "C" void kernel_launch(void* const* d_in, const int* in_sizes, int n_in,
                              void* d_out, int out_size, void* d_ws, size_t ws_size,
                              hipStream_t stream) {
  const float* x = (const float*)d_in[0];
  const float* src_mask = (const float*)d_in[1];
  const float* w_q = (const float*)d_in[2];
  const float* b_q = (const float*)d_in[3];
  const float* w_k = (const float*)d_in[4];
  const float* b_k = (const float*)d_in[5];
  const float* w_v = (const float*)d_in[6];
  const float* b_v = (const float*)d_in[7];
  const float* w_o = (const float*)d_in[8];
  const float* b_o = (const float*)d_in[9];
  const float* w_ff1 = (const float*)d_in[10];
  const float* b_ff1 = (const float*)d_in[11];
  const float* w_ff2 = (const float*)d_in[12];
  const float* b_ff2 = (const float*)d_in[13];
  const float* ln1_g = (const float*)d_in[14];
  const float* ln1_b = (const float*)d_in[15];
  const float* ln2_g = (const float*)d_in[16];
  const float* ln2_b = (const float*)d_in[17];

  char* ws = (char*)d_ws;
  constexpr size_t O_WQKVT = 0;                               // 3072x1024 bf16
  constexpr size_t O_WOT = O_WQKVT + 3072ull * 1024 * 2;      // 1024x1024 bf16
  constexpr size_t O_WFF1T = O_WOT + 1024ull * 1024 * 2;      // 4096x1024 bf16
  constexpr size_t O_WFF2T = O_WFF1T + 4096ull * 1024 * 2;    // 1024x4096 bf16
  constexpr size_t O_BQKV = O_WFF2T + 4096ull * 1024 * 2;     // 3072 f32
  constexpr size_t O_XBF = O_BQKV + 3072ull * 4;              // 4096x1024 bf16
  constexpr size_t O_QKV = O_XBF + 4096ull * 1024 * 2;        // 4096x3072 bf16
  constexpr size_t O_ATTN = O_QKV + 4096ull * 3072 * 2;       // 4096x1024 bf16
  constexpr size_t O_PROJ = O_ATTN + 4096ull * 1024 * 2;      // 4096x1024 f32
  constexpr size_t O_H1F = O_PROJ + 4096ull * 1024 * 4;       // 4096x1024 f32
  constexpr size_t O_H1B = O_H1F + 4096ull * 1024 * 4;        // 4096x1024 bf16
  constexpr size_t O_MASK2 = O_H1B + 4096ull * 1024 * 2;      // 4096 f32 (end)
  constexpr size_t O_VT = O_PROJ;   // 2x1024x2048 bf16 (dead before proj)
  constexpr size_t O_FF = O_QKV;    // 4096x4096 bf16 (reuse)
  constexpr size_t O_FF2 = O_PROJ;  // 4096x1024 f32 (reuse, after ln1)

  __bf16* wqkvT = (__bf16*)(ws + O_WQKVT);
  __bf16* woT = (__bf16*)(ws + O_WOT);
  __bf16* wff1T = (__bf16*)(ws + O_WFF1T);
  __bf16* wff2T = (__bf16*)(ws + O_WFF2T);
  float* bqkv = (float*)(ws + O_BQKV);
  __bf16* xbf = (__bf16*)(ws + O_XBF);
  __bf16* qkvb = (__bf16*)(ws + O_QKV);
  __bf16* attnb = (__bf16*)(ws + O_ATTN);
  float* proj = (float*)(ws + O_PROJ);
  float* h1f = (float*)(ws + O_H1F);
  __bf16* h1b = (__bf16*)(ws + O_H1B);
  float* mask2 = (float*)(ws + O_MASK2);
  __bf16* vT = (__bf16*)(ws + O_VT);
  __bf16* ffb = (__bf16*)(ws + O_FF);
  float* ff2 = (float*)(ws + O_FF2);

  // weight prep
  k_transpose_to_bf16<<<dim3(32, 32), 256, 0, stream>>>(w_q, wqkvT, 1024, 1024);
  k_transpose_to_bf16<<<dim3(32, 32), 256, 0, stream>>>(w_k, wqkvT + 1024 * 1024, 1024, 1024);
  k_transpose_to_bf16<<<dim3(32, 32), 256, 0, stream>>>(w_v, wqkvT + 2 * 1024 * 1024, 1024, 1024);
  k_transpose_to_bf16<<<dim3(32, 32), 256, 0, stream>>>(w_o, woT, 1024, 1024);
  k_transpose_to_bf16<<<dim3(128, 32), 256, 0, stream>>>(w_ff1, wff1T, 1024, 4096);
  k_transpose_to_bf16<<<dim3(32, 128), 256, 0, stream>>>(w_ff2, wff2T, 4096, 1024);
  k_concat3<<<12, 256, 0, stream>>>(b_q, b_k, b_v, bqkv);
  k_scale_mask<<<16, 256, 0, stream>>>(src_mask, mask2, BATCH * SEQ);
  k_cvt_bf16<<<4096, 256, 0, stream>>>(x, xbf, MTOT * DMODEL);

  // fused QKV projection (256^2 counted-vmcnt pipeline)
  k_gemm256<false, __bf16><<<dim3(12, 16), 512, 0, stream>>>(xbf, wqkvT, bqkv, qkvb,
                                                             MTOT, 3072, 1024);
  // V transpose for attention B-frags
  k_transpose_v<<<dim3(64, 32, 2), 256, 0, stream>>>(qkvb, vT);
  // attention (exp2-domain softmax + defer-max)
  k_attn<<<dim3(SEQ / 64, NHEAD, BATCH), 256, 0, stream>>>(qkvb, vT, mask2, attnb);
  // output projection (f32)
  k_gemm<2, false, float><<<dim3(8, 64), 256, 0, stream>>>(attnb, woT, b_o, proj,
                                                           MTOT, 1024, 1024);
  // ln1
  k_add_ln<<<4096, 256, 0, stream>>>(x, proj, ln1_g, ln1_b, h1f, h1b);
  // ff1 + relu (256^2 counted-vmcnt pipeline)
  k_gemm256<true, __bf16><<<dim3(16, 16), 512, 0, stream>>>(h1b, wff1T, b_ff1, ffb,
                                                            MTOT, DFF, 1024);
  // ff2
  k_gemm<2, false, float><<<dim3(8, 64), 256, 0, stream>>>(ffb, wff2T, b_ff2, ff2,
                                                           MTOT, 1024, DFF);
  // ln2 -> d_out
  k_add_ln<<<4096, 256, 0, stream>>>(h1f, ff2, ln2_g, ln2_b, (float*)d_out, nullptr);
}